// Round 3
// baseline (257.186 us; speedup 1.0000x reference)
//
#include <hip/hip_runtime.h>
#include <hip/hip_bf16.h>

// Problem constants (fixed by reference)
#define B_  4
#define E_  100000
#define N_  10000
#define NR_ 6
#define H_  256
#define D_  256
#define OUT_ 128

typedef __attribute__((ext_vector_type(4))) float f32x4;
typedef __attribute__((ext_vector_type(8))) short bf16x8;

__device__ __forceinline__ ushort f2bf(float f) {
  unsigned u = __builtin_bit_cast(unsigned, f);
  u += 0x7fffu + ((u >> 16) & 1u);  // round-to-nearest-even
  return (ushort)(u >> 16);
}

// ---------------------------------------------------------------------------
// CSR build: histogram -> scan -> fill
// ---------------------------------------------------------------------------
__global__ __launch_bounds__(256) void hist_kernel(const int* __restrict__ idx,
                                                   int* __restrict__ counts) {
  int e = blockIdx.x * 256 + threadIdx.x;
  if (e < E_) atomicAdd(&counts[idx[e]], 1);
}

__global__ __launch_bounds__(1024) void scan_kernel(
    const int* __restrict__ counts, int* __restrict__ starts,
    int* __restrict__ cursor) {
  __shared__ int sums[1024];
  const int t = threadIdx.x;
  const int base = t * 10;
  int loc[10];
  int s = 0;
#pragma unroll
  for (int j = 0; j < 10; ++j) {
    int v = (base + j < N_) ? counts[base + j] : 0;
    loc[j] = v;
    s += v;
  }
  sums[t] = s;
  __syncthreads();
  for (int off = 1; off < 1024; off <<= 1) {
    int v = (t >= off) ? sums[t - off] : 0;
    __syncthreads();
    sums[t] += v;
    __syncthreads();
  }
  int run = sums[t] - s;  // exclusive prefix
#pragma unroll
  for (int j = 0; j < 10; ++j) {
    if (base + j < N_) {
      starts[base + j] = run;
      cursor[base + j] = run;
      run += loc[j];
    }
  }
}

__global__ __launch_bounds__(256) void fill_kernel(const int* __restrict__ idx,
                                                   int* __restrict__ cursor,
                                                   int* __restrict__ buckets) {
  int e = blockIdx.x * 256 + threadIdx.x;
  if (e < E_) {
    int pos = atomicAdd(&cursor[idx[e]], 1);
    buckets[pos] = e;
  }
}

// ---------------------------------------------------------------------------
// Gather v2: one block per node. 256 thr = {b = tid>>6, t = tid&63},
// each thread owns h0 = 4t..4t+3 (float4 lane) for batch b.
// Bucket list prefetched to LDS; x read as float4 (wave = full 1KB row).
// ---------------------------------------------------------------------------
__global__ __launch_bounds__(256) void gather_kernel(
    const float* __restrict__ x, const float* __restrict__ rbf,
    const float* __restrict__ W_rbf, const int* __restrict__ starts,
    const int* __restrict__ counts, const int* __restrict__ buckets,
    ushort* __restrict__ agg) {
  __shared__ int elds[256];
  const int node = blockIdx.x;
  const int tid = threadIdx.x;
  const int b = tid >> 6;
  const int t = tid & 63;
  const int h0 = t * 4;

  f32x4 wrv[NR_];
#pragma unroll
  for (int r = 0; r < NR_; ++r)
    wrv[r] = *reinterpret_cast<const f32x4*>(&W_rbf[r * H_ + h0]);

  f32x4 acc = {0.f, 0.f, 0.f, 0.f};
  const int s = starts[node];
  const int d = counts[node];

  for (int c0 = 0; c0 < d; c0 += 256) {
    const int nc = min(256, d - c0);
    __syncthreads();  // protect elds reuse across chunks
    if (tid < nc) elds[tid] = buckets[s + c0 + tid];
    __syncthreads();
#pragma unroll 2
    for (int j = 0; j < nc; ++j) {
      const int e = elds[j];
      f32x4 rp = {0.f, 0.f, 0.f, 0.f};
#pragma unroll
      for (int r = 0; r < NR_; ++r) rp += rbf[e * NR_ + r] * wrv[r];
      const f32x4 xv = *reinterpret_cast<const f32x4*>(
          &x[((size_t)b * E_ + e) * H_ + h0]);
      acc += xv * rp;
    }
  }

  ushort4 o;
  o.x = f2bf(acc.x); o.y = f2bf(acc.y); o.z = f2bf(acc.z); o.w = f2bf(acc.w);
  *reinterpret_cast<ushort4*>(&agg[((size_t)b * N_ + node) * H_ + h0]) = o;
}

// ---------------------------------------------------------------------------
// Weight conversion: f32 [K][N] -> bf16 transposed [N][K], all 5 matrices.
// Concatenated dst: W_up^T(256x256) | Ws0^T | Ws1^T | Ws2^T | W_out^T(128x256)
// ---------------------------------------------------------------------------
__global__ __launch_bounds__(256) void convert_weights(
    const float* __restrict__ W_up, const float* __restrict__ Ws,
    const float* __restrict__ W_out, ushort* __restrict__ Wt) {
  const int id = blockIdx.x * 256 + threadIdx.x;  // < 294912
  const float* src;
  int base, Ncols;
  if (id < 65536) {
    src = W_up; base = 0; Ncols = 256;
  } else if (id < 4 * 65536) {
    int l = (id - 65536) >> 16;
    src = Ws + l * 65536; base = (1 + l) * 65536; Ncols = 256;
  } else {
    src = W_out; base = 4 * 65536; Ncols = 128;
  }
  const int loc = id - base;
  const int n = loc >> 8;    // dst row  (0..Ncols-1)
  const int k = loc & 255;   // dst col  (0..255)
  Wt[id] = f2bf(src[k * Ncols + n]);
}

// ---------------------------------------------------------------------------
// Fused 5-layer chain: act tile [32 rows][256 cols] bf16 resident in LDS
// (XOR-swizzled: byte ^= (row&7)<<4), B-fragments read from L2-resident
// transposed bf16 weights. 4 waves, each owns a 64-col strip (32 on final).
// 2 barriers per layer (read-phase | write-phase on the single LDS buffer).
// ---------------------------------------------------------------------------
__global__ __launch_bounds__(256, 5) void chain_kernel(
    const ushort* __restrict__ agg, const ushort* __restrict__ Wt,
    const float* __restrict__ bs, float* __restrict__ out) {
  __shared__ ushort act[32 * 256];  // 16 KB
  char* actb = reinterpret_cast<char*>(act);
  const int row0 = blockIdx.x * 32;
  const int tid = threadIdx.x;
  const int wave = tid >> 6;
  const int lane = tid & 63;
  const int lr = lane & 15;
  const int lq = lane >> 4;

  // --- stage agg tile into LDS, swizzled (reg-staged; coalesced 16B) ---
#pragma unroll
  for (int t = 0; t < 4; ++t) {
    const int idx = tid + t * 256;  // 16B-chunk id, 0..1023
    const int row = idx >> 5;
    const int s = idx & 31;
    const uint4 v = *reinterpret_cast<const uint4*>(
        &agg[(size_t)(row0 + row) * 256 + s * 8]);
    const int byte = (row * 512 + s * 16) ^ ((row & 7) << 4);
    *reinterpret_cast<uint4*>(actb + byte) = v;
  }
  __syncthreads();

  // --- layers 0..3: 256 -> 256 (l=0: W_up no bias; l>=1: silu(.+bs[l-1])) ---
  for (int l = 0; l < 4; ++l) {
    const ushort* W = Wt + l * 65536;
    const int wc = wave * 64;
    f32x4 acc[2][4] = {};
#pragma unroll
    for (int ks = 0; ks < 8; ++ks) {
      bf16x8 af[2], bfr[4];
#pragma unroll
      for (int m = 0; m < 2; ++m) {
        const int row = m * 16 + lr;
        const int byte = (row * 512 + ks * 64 + lq * 16) ^ ((row & 7) << 4);
        af[m] = *reinterpret_cast<const bf16x8*>(actb + byte);
      }
#pragma unroll
      for (int n = 0; n < 4; ++n) {
        const int col = wc + n * 16 + lr;
        bfr[n] = *reinterpret_cast<const bf16x8*>(&W[col * 256 + ks * 32 + lq * 8]);
      }
#pragma unroll
      for (int m = 0; m < 2; ++m)
#pragma unroll
        for (int n = 0; n < 4; ++n)
          acc[m][n] = __builtin_amdgcn_mfma_f32_16x16x32_bf16(af[m], bfr[n],
                                                              acc[m][n], 0, 0, 0);
    }
    __syncthreads();  // all waves done READING act for this layer

    const bool ba = (l > 0);
#pragma unroll
    for (int n = 0; n < 4; ++n) {
      const int col = wc + n * 16 + lr;
      const float bv = ba ? bs[(l - 1) * 256 + col] : 0.f;
#pragma unroll
      for (int m = 0; m < 2; ++m) {
#pragma unroll
        for (int r = 0; r < 4; ++r) {
          float v = acc[m][n][r];
          if (ba) {
            v += bv;
            v = v / (1.0f + __expf(-v));  // SiLU
          }
          const int row = m * 16 + lq * 4 + r;
          const int byte = (row * 512 + col * 2) ^ ((row & 7) << 4);
          *reinterpret_cast<ushort*>(actb + byte) = f2bf(v);
        }
      }
    }
    __syncthreads();  // writes visible before next layer reads
  }

  // --- final layer: 256 -> 128, f32 output ---
  {
    const ushort* W = Wt + 4 * 65536;
    const int wc = wave * 32;
    f32x4 acc[2][2] = {};
#pragma unroll
    for (int ks = 0; ks < 8; ++ks) {
      bf16x8 af[2], bfr[2];
#pragma unroll
      for (int m = 0; m < 2; ++m) {
        const int row = m * 16 + lr;
        const int byte = (row * 512 + ks * 64 + lq * 16) ^ ((row & 7) << 4);
        af[m] = *reinterpret_cast<const bf16x8*>(actb + byte);
      }
#pragma unroll
      for (int n = 0; n < 2; ++n) {
        const int col = wc + n * 16 + lr;
        bfr[n] = *reinterpret_cast<const bf16x8*>(&W[col * 256 + ks * 32 + lq * 8]);
      }
#pragma unroll
      for (int m = 0; m < 2; ++m)
#pragma unroll
        for (int n = 0; n < 2; ++n)
          acc[m][n] = __builtin_amdgcn_mfma_f32_16x16x32_bf16(af[m], bfr[n],
                                                              acc[m][n], 0, 0, 0);
    }
#pragma unroll
    for (int m = 0; m < 2; ++m)
#pragma unroll
      for (int n = 0; n < 2; ++n)
#pragma unroll
        for (int r = 0; r < 4; ++r) {
          const int row = row0 + m * 16 + lq * 4 + r;
          const int col = wc + n * 16 + lr;
          out[(size_t)row * OUT_ + col] = acc[m][n][r];
        }
  }
}

// ---------------------------------------------------------------------------
extern "C" void kernel_launch(void* const* d_in, const int* in_sizes, int n_in,
                              void* d_out, int out_size, void* d_ws,
                              size_t ws_size, hipStream_t stream) {
  const float* x     = (const float*)d_in[0];  // [B,E,H]
  const float* rbf   = (const float*)d_in[1];  // [E,NR]
  const int*   idx   = (const int*)d_in[2];    // [E]
  const float* W_rbf = (const float*)d_in[3];  // [NR,H]
  const float* W_up  = (const float*)d_in[4];  // [H,D]
  const float* Ws    = (const float*)d_in[5];  // [L,D,D]
  const float* bs    = (const float*)d_in[6];  // [L,D]
  const float* W_out = (const float*)d_in[7];  // [D,OUT]
  float* out = (float*)d_out;                  // [B,N,OUT] f32

  // workspace layout (bytes)
  char* ws = (char*)d_ws;
  const size_t agg_bytes = (size_t)B_ * N_ * H_ * sizeof(ushort);  // 20.48 MB
  ushort* agg = (ushort*)(ws);
  ushort* Wt  = (ushort*)(ws + agg_bytes);  // 294912 bf16
  char* ibase = ws + agg_bytes + 294912 * sizeof(ushort);
  int* counts  = (int*)(ibase);
  int* starts  = (int*)(ibase + 40000);
  int* cursor  = (int*)(ibase + 80000);
  int* buckets = (int*)(ibase + 120000);

  // CSR build
  hipMemsetAsync(counts, 0, N_ * sizeof(int), stream);
  hist_kernel<<<(E_ + 255) / 256, 256, 0, stream>>>(idx, counts);
  scan_kernel<<<1, 1024, 0, stream>>>(counts, starts, cursor);
  fill_kernel<<<(E_ + 255) / 256, 256, 0, stream>>>(idx, cursor, buckets);

  // weights -> bf16 transposed (independent of CSR chain)
  convert_weights<<<294912 / 256, 256, 0, stream>>>(W_up, Ws, W_out, Wt);

  // gather-aggregate into bf16 agg
  gather_kernel<<<N_, 256, 0, stream>>>(x, rbf, W_rbf, starts, counts, buckets,
                                        agg);

  // fused 5-layer chain, 40000/32 = 1250 row-tiles
  chain_kernel<<<1250, 256, 0, stream>>>(agg, Wt, bs, out);
}

// Round 4
// 195.805 us; speedup vs baseline: 1.3135x; 1.3135x over previous
//
#include <hip/hip_runtime.h>
#include <hip/hip_bf16.h>

// Problem constants (fixed by reference)
#define B_  4
#define E_  100000
#define N_  10000
#define NR_ 6
#define H_  256
#define D_  256
#define OUT_ 128

typedef __attribute__((ext_vector_type(4))) float f32x4;
typedef __attribute__((ext_vector_type(8))) short bf16x8;

__device__ __forceinline__ ushort f2bf(float f) {
  unsigned u = __builtin_bit_cast(unsigned, f);
  u += 0x7fffu + ((u >> 16) & 1u);  // round-to-nearest-even
  return (ushort)(u >> 16);
}

// ---------------------------------------------------------------------------
// CSR build: histogram -> scan -> fill
// ---------------------------------------------------------------------------
__global__ __launch_bounds__(256) void hist_kernel(const int* __restrict__ idx,
                                                   int* __restrict__ counts) {
  int e = blockIdx.x * 256 + threadIdx.x;
  if (e < E_) atomicAdd(&counts[idx[e]], 1);
}

__global__ __launch_bounds__(1024) void scan_kernel(
    const int* __restrict__ counts, int* __restrict__ starts,
    int* __restrict__ cursor) {
  __shared__ int sums[1024];
  const int t = threadIdx.x;
  const int base = t * 10;
  int loc[10];
  int s = 0;
#pragma unroll
  for (int j = 0; j < 10; ++j) {
    int v = (base + j < N_) ? counts[base + j] : 0;
    loc[j] = v;
    s += v;
  }
  sums[t] = s;
  __syncthreads();
  for (int off = 1; off < 1024; off <<= 1) {
    int v = (t >= off) ? sums[t - off] : 0;
    __syncthreads();
    sums[t] += v;
    __syncthreads();
  }
  int run = sums[t] - s;  // exclusive prefix
#pragma unroll
  for (int j = 0; j < 10; ++j) {
    if (base + j < N_) {
      starts[base + j] = run;
      cursor[base + j] = run;
      run += loc[j];
    }
  }
}

__global__ __launch_bounds__(256) void fill_kernel(const int* __restrict__ idx,
                                                   int* __restrict__ cursor,
                                                   int* __restrict__ buckets) {
  int e = blockIdx.x * 256 + threadIdx.x;
  if (e < E_) {
    int pos = atomicAdd(&cursor[idx[e]], 1);
    buckets[pos] = e;
  }
}

// ---------------------------------------------------------------------------
// Gather: one block per node. 256 thr = {b = tid>>6, t = tid&63},
// thread owns h0 = 4t..4t+3 (float4) for batch b. unroll 4 for MLP depth.
// ---------------------------------------------------------------------------
__global__ __launch_bounds__(256) void gather_kernel(
    const float* __restrict__ x, const float* __restrict__ rbf,
    const float* __restrict__ W_rbf, const int* __restrict__ starts,
    const int* __restrict__ counts, const int* __restrict__ buckets,
    ushort* __restrict__ agg) {
  __shared__ int elds[256];
  const int node = blockIdx.x;
  const int tid = threadIdx.x;
  const int b = tid >> 6;
  const int t = tid & 63;
  const int h0 = t * 4;

  f32x4 wrv[NR_];
#pragma unroll
  for (int r = 0; r < NR_; ++r)
    wrv[r] = *reinterpret_cast<const f32x4*>(&W_rbf[r * H_ + h0]);

  f32x4 acc = {0.f, 0.f, 0.f, 0.f};
  const int s = starts[node];
  const int d = counts[node];

  for (int c0 = 0; c0 < d; c0 += 256) {
    const int nc = min(256, d - c0);
    __syncthreads();  // protect elds reuse across chunks
    if (tid < nc) elds[tid] = buckets[s + c0 + tid];
    __syncthreads();
#pragma unroll 4
    for (int j = 0; j < nc; ++j) {
      const int e = elds[j];
      f32x4 rp = {0.f, 0.f, 0.f, 0.f};
#pragma unroll
      for (int r = 0; r < NR_; ++r) rp += rbf[e * NR_ + r] * wrv[r];
      const f32x4 xv = *reinterpret_cast<const f32x4*>(
          &x[((size_t)b * E_ + e) * H_ + h0]);
      acc += xv * rp;
    }
  }

  ushort4 o;
  o.x = f2bf(acc.x); o.y = f2bf(acc.y); o.z = f2bf(acc.z); o.w = f2bf(acc.w);
  *reinterpret_cast<ushort4*>(&agg[((size_t)b * N_ + node) * H_ + h0]) = o;
}

// ---------------------------------------------------------------------------
// Weight packing: f32 [K][C] -> bf16 in MFMA B-fragment order:
//   Wp[l][nb][ks][lane][8],  element = W_l[k = ks*32+(lane>>4)*8+j][col = nb*16+(lane&15)]
// so a wave's B-frag load (16x16x32 tile nb, k-step ks) is 64 lanes x 16B
// fully coalesced. Layer bases (elems): l*65536 (l<4), 262144 (l=4).
// ---------------------------------------------------------------------------
__global__ __launch_bounds__(256) void convert_weights(
    const float* __restrict__ W_up, const float* __restrict__ Ws,
    const float* __restrict__ W_out, ushort* __restrict__ Wp) {
  const int g = blockIdx.x * 256 + threadIdx.x;  // group id < 36864
  int l, goff, Ncols;
  if (g < 32768) { l = g >> 13; goff = g & 8191; Ncols = 256; }
  else           { l = 4;       goff = g - 32768; Ncols = 128; }
  const float* src = (l == 0) ? W_up : (l < 4 ? Ws + (l - 1) * 65536 : W_out);
  const int lane = goff & 63;
  const int ks   = (goff >> 6) & 7;
  const int nb   = goff >> 9;
  const int col  = nb * 16 + (lane & 15);
  const int k0   = ks * 32 + (lane >> 4) * 8;
  ushort tmp[8];
#pragma unroll
  for (int j = 0; j < 8; ++j)
    tmp[j] = f2bf(src[(size_t)(k0 + j) * Ncols + col]);
  *reinterpret_cast<uint4*>(&Wp[(size_t)g * 8]) =
      *reinterpret_cast<const uint4*>(tmp);
}

// ---------------------------------------------------------------------------
// Fused 5-layer chain v2: BM=64 rows/block, 512 thr (8 waves, 2x4).
// act [64][256] bf16 in LDS, XOR-swizzled (byte ^= (row&7)<<4).
// B-frags stream coalesced from pre-packed L2-resident weights.
// ---------------------------------------------------------------------------
__global__ __launch_bounds__(512) void chain_kernel(
    const ushort* __restrict__ agg, const ushort* __restrict__ Wp,
    const float* __restrict__ bs, float* __restrict__ out) {
  __shared__ ushort act[64 * 256];  // 32 KB
  char* actb = reinterpret_cast<char*>(act);
  const int row0 = blockIdx.x * 64;
  const int tid = threadIdx.x;
  const int wave = tid >> 6;
  const int lane = tid & 63;
  const int lr = lane & 15;
  const int lq = lane >> 4;
  const int wr = wave >> 2;  // 0..1 : 32-row strip
  const int wc = wave & 3;   // 0..3 : 64-col strip (32-col on final)

  // --- stage agg tile into LDS, swizzled ---
#pragma unroll
  for (int t = 0; t < 4; ++t) {
    const int idx = tid + t * 512;  // 16B-chunk id, 0..2047
    const int row = idx >> 5;
    const int s = idx & 31;
    const uint4 v = *reinterpret_cast<const uint4*>(
        &agg[(size_t)(row0 + row) * 256 + s * 8]);
    const int byte = (row * 512 + s * 16) ^ ((row & 7) << 4);
    *reinterpret_cast<uint4*>(actb + byte) = v;
  }
  __syncthreads();

  // --- layers 0..3: 256 -> 256 (l=0: W_up, no act; l>=1: silu(.+bs[l-1])) ---
  for (int l = 0; l < 4; ++l) {
    const ushort* W = Wp + l * 65536;
    f32x4 acc[2][4] = {};
#pragma unroll
    for (int ks = 0; ks < 8; ++ks) {
      bf16x8 af[2], bfr[4];
#pragma unroll
      for (int m = 0; m < 2; ++m) {
        const int row = wr * 32 + m * 16 + lr;
        const int byte = (row * 512 + ks * 64 + lq * 16) ^ ((row & 7) << 4);
        af[m] = *reinterpret_cast<const bf16x8*>(actb + byte);
      }
#pragma unroll
      for (int n = 0; n < 4; ++n) {
        const int nb = wc * 4 + n;
        bfr[n] = *reinterpret_cast<const bf16x8*>(
            &W[(size_t)(((nb * 8 + ks) * 64) + lane) * 8]);
      }
#pragma unroll
      for (int m = 0; m < 2; ++m)
#pragma unroll
        for (int n = 0; n < 4; ++n)
          acc[m][n] = __builtin_amdgcn_mfma_f32_16x16x32_bf16(af[m], bfr[n],
                                                              acc[m][n], 0, 0, 0);
    }
    __syncthreads();  // all waves done READING act for this layer

    const bool ba = (l > 0);
#pragma unroll
    for (int n = 0; n < 4; ++n) {
      const int col = wc * 64 + n * 16 + lr;
      const float bv = ba ? bs[(l - 1) * 256 + col] : 0.f;
#pragma unroll
      for (int m = 0; m < 2; ++m) {
#pragma unroll
        for (int r = 0; r < 4; ++r) {
          float v = acc[m][n][r];
          if (ba) {
            v += bv;
            v = v / (1.0f + __expf(-v));  // SiLU
          }
          const int row = wr * 32 + m * 16 + lq * 4 + r;
          const int byte = (row * 512 + col * 2) ^ ((row & 7) << 4);
          *reinterpret_cast<ushort*>(actb + byte) = f2bf(v);
        }
      }
    }
    __syncthreads();  // writes visible before next layer reads
  }

  // --- final layer: 256 -> 128, f32 output. Wave tile 32 rows x 32 cols ---
  {
    const ushort* W = Wp + 4 * 65536;
    f32x4 acc[2][2] = {};
#pragma unroll
    for (int ks = 0; ks < 8; ++ks) {
      bf16x8 af[2], bfr[2];
#pragma unroll
      for (int m = 0; m < 2; ++m) {
        const int row = wr * 32 + m * 16 + lr;
        const int byte = (row * 512 + ks * 64 + lq * 16) ^ ((row & 7) << 4);
        af[m] = *reinterpret_cast<const bf16x8*>(actb + byte);
      }
#pragma unroll
      for (int n = 0; n < 2; ++n) {
        const int nb = wc * 2 + n;
        bfr[n] = *reinterpret_cast<const bf16x8*>(
            &W[(size_t)(((nb * 8 + ks) * 64) + lane) * 8]);
      }
#pragma unroll
      for (int m = 0; m < 2; ++m)
#pragma unroll
        for (int n = 0; n < 2; ++n)
          acc[m][n] = __builtin_amdgcn_mfma_f32_16x16x32_bf16(af[m], bfr[n],
                                                              acc[m][n], 0, 0, 0);
    }
#pragma unroll
    for (int m = 0; m < 2; ++m)
#pragma unroll
      for (int n = 0; n < 2; ++n)
#pragma unroll
        for (int r = 0; r < 4; ++r) {
          const int row = row0 + wr * 32 + m * 16 + lq * 4 + r;
          const int col = wc * 32 + n * 16 + lr;
          out[(size_t)row * OUT_ + col] = acc[m][n][r];
        }
  }
}

// ---------------------------------------------------------------------------
extern "C" void kernel_launch(void* const* d_in, const int* in_sizes, int n_in,
                              void* d_out, int out_size, void* d_ws,
                              size_t ws_size, hipStream_t stream) {
  const float* x     = (const float*)d_in[0];  // [B,E,H]
  const float* rbf   = (const float*)d_in[1];  // [E,NR]
  const int*   idx   = (const int*)d_in[2];    // [E]
  const float* W_rbf = (const float*)d_in[3];  // [NR,H]
  const float* W_up  = (const float*)d_in[4];  // [H,D]
  const float* Ws    = (const float*)d_in[5];  // [L,D,D]
  const float* bs    = (const float*)d_in[6];  // [L,D]
  const float* W_out = (const float*)d_in[7];  // [D,OUT]
  float* out = (float*)d_out;                  // [B,N,OUT] f32

  // workspace layout (bytes)
  char* ws = (char*)d_ws;
  const size_t agg_bytes = (size_t)B_ * N_ * H_ * sizeof(ushort);  // 20.48 MB
  ushort* agg = (ushort*)(ws);
  ushort* Wp  = (ushort*)(ws + agg_bytes);  // 294912 bf16
  char* ibase = ws + agg_bytes + 294912 * sizeof(ushort);
  int* counts  = (int*)(ibase);
  int* starts  = (int*)(ibase + 40000);
  int* cursor  = (int*)(ibase + 80000);
  int* buckets = (int*)(ibase + 120000);

  // CSR build
  hipMemsetAsync(counts, 0, N_ * sizeof(int), stream);
  hist_kernel<<<(E_ + 255) / 256, 256, 0, stream>>>(idx, counts);
  scan_kernel<<<1, 1024, 0, stream>>>(counts, starts, cursor);
  fill_kernel<<<(E_ + 255) / 256, 256, 0, stream>>>(idx, cursor, buckets);

  // weights -> packed bf16 fragments (independent of CSR chain)
  convert_weights<<<36864 / 256, 256, 0, stream>>>(W_up, Ws, W_out, Wp);

  // gather-aggregate into bf16 agg
  gather_kernel<<<N_, 256, 0, stream>>>(x, rbf, W_rbf, starts, counts, buckets,
                                        agg);

  // fused 5-layer chain, 40000/64 = 625 row-tiles
  chain_kernel<<<625, 512, 0, stream>>>(agg, Wp, bs, out);
}